// Round 1
// baseline (252.050 us; speedup 1.0000x reference)
//
#include <hip/hip_runtime.h>

typedef int i32x4 __attribute__((ext_vector_type(4)));

#define AS1 __attribute__((address_space(1)))
#define AS3 __attribute__((address_space(3)))

// ---------------------------------------------------------------------------
// Quantize kernel (UNCHANGED from verified version). Blocks [0, M): per-token
// dynamic quant of x row r (4096 fp32 -> int8, scale sx[r] = rowmax/127).
// Blocks [M, M+wB): narrow w int32 (values 0..126, exact) -> int8.
// ---------------------------------------------------------------------------
__global__ __launch_bounds__(256) void quant_kernel(
    const float4* __restrict__ x, const int4* __restrict__ w,
    signed char* __restrict__ xq, signed char* __restrict__ wq,
    float* __restrict__ sx, int M, int Kq) {
  const int tid = threadIdx.x;
  if ((int)blockIdx.x < M) {
    const int r = blockIdx.x;
    float4 v[4];
    #pragma unroll
    for (int j = 0; j < 4; ++j) v[j] = x[(size_t)r * 1024 + tid * 4 + j];
    float m = 0.f;
    #pragma unroll
    for (int j = 0; j < 4; ++j)
      m = fmaxf(m, fmaxf(fmaxf(fabsf(v[j].x), fabsf(v[j].y)),
                         fmaxf(fabsf(v[j].z), fabsf(v[j].w))));
    #pragma unroll
    for (int off = 1; off < 64; off <<= 1) m = fmaxf(m, __shfl_xor(m, off));
    __shared__ float wmax[4];
    if ((tid & 63) == 0) wmax[tid >> 6] = m;
    __syncthreads();
    m = fmaxf(fmaxf(wmax[0], wmax[1]), fmaxf(wmax[2], wmax[3]));
    const float inv = (m > 0.f) ? 127.0f / m : 0.f;
    if (tid == 0) sx[r] = m * (1.0f / 127.0f);
    signed char q[16];
    #pragma unroll
    for (int j = 0; j < 4; ++j) {
      q[j * 4 + 0] = (signed char)__float2int_rn(v[j].x * inv);
      q[j * 4 + 1] = (signed char)__float2int_rn(v[j].y * inv);
      q[j * 4 + 2] = (signed char)__float2int_rn(v[j].z * inv);
      q[j * 4 + 3] = (signed char)__float2int_rn(v[j].w * inv);
    }
    ((int4*)xq)[(size_t)r * 256 + tid] = *(const int4*)q;
  } else {
    const int b = blockIdx.x - M;
    int4 v[4];
    #pragma unroll
    for (int j = 0; j < 4; ++j) v[j] = w[(size_t)b * 1024 + tid * 4 + j];
    signed char q[16];
    #pragma unroll
    for (int j = 0; j < 4; ++j) {
      q[j * 4 + 0] = (signed char)v[j].x; q[j * 4 + 1] = (signed char)v[j].y;
      q[j * 4 + 2] = (signed char)v[j].z; q[j * 4 + 3] = (signed char)v[j].w;
    }
    ((int4*)wq)[(size_t)b * 256 + tid] = *(const int4*)q;
  }
}

// ---------------------------------------------------------------------------
// C[M][N] = (Aq[M][K] . Bq[N][K]^T) * sx[M] * scaler[N]
//
// 8-phase-style schedule (T2+T3+T4+T5 port of the 256^2 bf16 template):
//   tile 256x256, BK=64 (i8 rows = 64B), 512 thr = 8 waves (2M x 4N),
//   per-wave output 128x64, mfma_i32_16x16x64_i8.
// LDS: 4-deep ring, 4 x (sA 16KB + sB 16KB) = 128 KB.
//   Tile t is read from buf[t&3]; tile t+2 is staged into buf[(t+2)&3],
//   which was last READ at tile t-2 (two barrier-separated iterations ago)
//   -> staging writes can land at any time; no read/write race possible.
// Per K-tile: 2 phases, each {issue 2 global_load_lds ; 4-8 ds_read_b128 ;
//   s_barrier ; setprio(1) ; 16 MFMA ; setprio(0) ; s_barrier}.
// vmcnt: counted vmcnt(4) ONCE per tile (allows tile t+2's 4 loads to stay
//   in flight; guarantees tile t+1 landed). Never drains to 0 in main loop.
// Swizzle (64B rows, 4 x 16B slots): phys_slot = logical ^ ((row>>1)&3),
//   applied to the pre-swizzled GLOBAL source (LDS dest stays linear, as
//   global_load_lds requires) and to the ds_read address. Gives uniform
//   8 lanes per 4-bank group for ds_read_b128 -> conflict-free.
// ---------------------------------------------------------------------------
__global__ __launch_bounds__(512, 2) void gemm_i8_kernel(
    const signed char* __restrict__ A,   // [M][K] i8
    const signed char* __restrict__ B,   // [N][K] i8
    const float* __restrict__ sx,        // [M] x dequant scale
    const float* __restrict__ scaler,    // [N] weight scale
    float* __restrict__ C,               // [M][N] fp32
    int M, int N, int K)
{
  __shared__ signed char sA[4][256 * 64];   // 4 x 16 KB
  __shared__ signed char sB[4][256 * 64];   // 4 x 16 KB

  const int tid  = threadIdx.x;
  const int wave = tid >> 6;
  const int lane = tid & 63;
  const int bm = blockIdx.y << 8;
  const int bn = blockIdx.x << 8;

  const int wm = (wave >> 2) << 7;   // 0 or 128 : wave's M offset
  const int wn = (wave & 3) << 6;    // 0/64/128/192 : wave's N offset
  const int l15  = lane & 15;
  const int quad = lane >> 4;

  // Staging: thread t covers row (t>>2) (round 0) / 128+(t>>2) (round 1),
  // physical 16B slot (t&3). Its logical k-group = (t&3) ^ ((row>>1)&3);
  // note (row+128)>>1 & 3 == row>>1 & 3, so one kg serves both rounds.
  const int srow = tid >> 2;
  const int kg = (tid & 3) ^ ((srow >> 1) & 3);
  const signed char* ga = A + (size_t)(bm + srow) * K + kg * 16;
  const signed char* gb = B + (size_t)(bn + srow) * K + kg * 16;
  const size_t rstep = (size_t)128 * K;     // +128 rows (round 1)
  const int ldst = tid * 16;                // linear LDS dest

  // Fragment ds_read: row = (wm|wn) + frag*16 + l15, logical kgroup = quad,
  // phys = quad ^ ((l15>>1)&3)  (frag*16 and wm/wn don't affect (row>>1)&3).
  const int pk   = (quad ^ ((l15 >> 1) & 3)) << 4;
  const int aoff = (wm + l15) * 64 + pk;    // + mi*1024 per fragment
  const int boff = (wn + l15) * 64 + pk;    // + ni*1024 per fragment

  i32x4 acc[8][4] = {};

#define STAGE_A(tt) do { const int sb_ = (tt) & 3;                           \
    __builtin_amdgcn_global_load_lds((AS1 void*)(ga + (size_t)(tt) * 64),    \
                                     (AS3 void*)(&sA[sb_][ldst]), 16, 0, 0); \
    __builtin_amdgcn_global_load_lds((AS1 void*)(ga + (size_t)(tt) * 64 + rstep), \
                                     (AS3 void*)(&sA[sb_][8192 + ldst]), 16, 0, 0); } while (0)
#define STAGE_B(tt) do { const int sb_ = (tt) & 3;                           \
    __builtin_amdgcn_global_load_lds((AS1 void*)(gb + (size_t)(tt) * 64),    \
                                     (AS3 void*)(&sB[sb_][ldst]), 16, 0, 0); \
    __builtin_amdgcn_global_load_lds((AS1 void*)(gb + (size_t)(tt) * 64 + rstep), \
                                     (AS3 void*)(&sB[sb_][8192 + ldst]), 16, 0, 0); } while (0)

  const int nt = K >> 6;                    // 64 K-tiles

  // Prologue: stage tiles 0 and 1 (8 loads); wait until tile 0's 4 landed.
  STAGE_A(0); STAGE_B(0); STAGE_A(1); STAGE_B(1);
  asm volatile("s_waitcnt vmcnt(4)" ::: "memory");
  __builtin_amdgcn_s_barrier();
  __builtin_amdgcn_sched_barrier(0);

  for (int t = 0; t < nt; ++t) {
    const signed char* la = sA[t & 3];
    const signed char* lb = sB[t & 3];
    const bool st = (t < nt - 2);
    i32x4 av[4], bv[4];

    // ---- phase 0: stage A-half of t+2 ; read B0-3, A0-3 ; MFMA m0-3 x n0-3
    if (st) STAGE_A(t + 2);
    #pragma unroll
    for (int ni = 0; ni < 4; ++ni) bv[ni] = *(const i32x4*)&lb[boff + ni * 1024];
    #pragma unroll
    for (int mi = 0; mi < 4; ++mi) av[mi] = *(const i32x4*)&la[aoff + mi * 1024];
    __builtin_amdgcn_s_barrier();
    __builtin_amdgcn_s_setprio(1);
    #pragma unroll
    for (int mi = 0; mi < 4; ++mi)
      #pragma unroll
      for (int ni = 0; ni < 4; ++ni)
        acc[mi][ni] = __builtin_amdgcn_mfma_i32_16x16x64_i8(av[mi], bv[ni], acc[mi][ni], 0, 0, 0);
    __builtin_amdgcn_s_setprio(0);
    __builtin_amdgcn_s_barrier();

    // ---- phase 1: stage B-half of t+2 ; read A4-7 (reuse B regs) ; MFMA
    if (st) STAGE_B(t + 2);
    #pragma unroll
    for (int mi = 0; mi < 4; ++mi) av[mi] = *(const i32x4*)&la[aoff + (mi + 4) * 1024];
    __builtin_amdgcn_s_barrier();
    __builtin_amdgcn_s_setprio(1);
    #pragma unroll
    for (int mi = 0; mi < 4; ++mi)
      #pragma unroll
      for (int ni = 0; ni < 4; ++ni)
        acc[mi + 4][ni] = __builtin_amdgcn_mfma_i32_16x16x64_i8(av[mi], bv[ni], acc[mi + 4][ni], 0, 0, 0);
    __builtin_amdgcn_s_setprio(0);

    // ---- tile boundary: tile t+1 must be landed; tile t+2's 4 loads may fly
    if (st)                 asm volatile("s_waitcnt vmcnt(4)" ::: "memory");
    else if (t == nt - 2)   asm volatile("s_waitcnt vmcnt(0)" ::: "memory");
    __builtin_amdgcn_s_barrier();
    __builtin_amdgcn_sched_barrier(0);
  }
#undef STAGE_A
#undef STAGE_B

  // Epilogue: C/D layout col=lane&15 (N), row=quad*4+reg (M) — dtype-indep.
  #pragma unroll
  for (int mi = 0; mi < 8; ++mi) {
    const int gm0 = bm + wm + mi * 16 + quad * 4;
    float sr[4];
    #pragma unroll
    for (int r = 0; r < 4; ++r) sr[r] = sx[gm0 + r];
    #pragma unroll
    for (int ni = 0; ni < 4; ++ni) {
      const int gn = bn + wn + ni * 16 + l15;
      const float sc = scaler[gn];
      #pragma unroll
      for (int r = 0; r < 4; ++r)
        C[(size_t)(gm0 + r) * N + gn] = (float)acc[mi][ni][r] * sr[r] * sc;
    }
  }
}

extern "C" void kernel_launch(void* const* d_in, const int* in_sizes, int n_in,
                              void* d_out, int out_size, void* d_ws, size_t ws_size,
                              hipStream_t stream) {
  const float* x  = (const float*)d_in[0];          // [B,S,K] fp32
  const int*   w  = (const int*)d_in[1];            // [N,K] int32 (int8 range)
  const float* sc = (const float*)d_in[2];          // [N] fp32
  float* out = (float*)d_out;

  const int N = in_sizes[2];                        // 4096
  const int K = in_sizes[1] / N;                    // 4096
  const int M = in_sizes[0] / K;                    // 4096

  signed char* Aq = (signed char*)d_ws;             // [M][K] i8
  signed char* Bq = Aq + (size_t)M * K;             // [N][K] i8
  float* sx = (float*)(Bq + (size_t)N * K);         // [M] fp32

  const int wBlocks = (N * K) / (256 * 16);         // 16 elems/thread
  quant_kernel<<<M + wBlocks, 256, 0, stream>>>(
      (const float4*)x, (const int4*)w, Aq, Bq, sx, M, K / 16);

  dim3 grid(N / 256, M / 256);
  gemm_i8_kernel<<<grid, 512, 0, stream>>>(Aq, Bq, sx, sc, out, M, N, K);
}

// Round 2
// 251.243 us; speedup vs baseline: 1.0032x; 1.0032x over previous
//
#include <hip/hip_runtime.h>

typedef int i32x4 __attribute__((ext_vector_type(4)));

#define AS1 __attribute__((address_space(1)))
#define AS3 __attribute__((address_space(3)))

// ---------------------------------------------------------------------------
// Quantize kernel (UNCHANGED from verified version). Blocks [0, M): per-token
// dynamic quant of x row r (4096 fp32 -> int8, scale sx[r] = rowmax/127).
// Blocks [M, M+wB): narrow w int32 (values 0..126, exact) -> int8.
// ---------------------------------------------------------------------------
__global__ __launch_bounds__(256) void quant_kernel(
    const float4* __restrict__ x, const int4* __restrict__ w,
    signed char* __restrict__ xq, signed char* __restrict__ wq,
    float* __restrict__ sx, int M, int Kq) {
  const int tid = threadIdx.x;
  if ((int)blockIdx.x < M) {
    const int r = blockIdx.x;
    float4 v[4];
    #pragma unroll
    for (int j = 0; j < 4; ++j) v[j] = x[(size_t)r * 1024 + tid * 4 + j];
    float m = 0.f;
    #pragma unroll
    for (int j = 0; j < 4; ++j)
      m = fmaxf(m, fmaxf(fmaxf(fabsf(v[j].x), fabsf(v[j].y)),
                         fmaxf(fabsf(v[j].z), fabsf(v[j].w))));
    #pragma unroll
    for (int off = 1; off < 64; off <<= 1) m = fmaxf(m, __shfl_xor(m, off));
    __shared__ float wmax[4];
    if ((tid & 63) == 0) wmax[tid >> 6] = m;
    __syncthreads();
    m = fmaxf(fmaxf(wmax[0], wmax[1]), fmaxf(wmax[2], wmax[3]));
    const float inv = (m > 0.f) ? 127.0f / m : 0.f;
    if (tid == 0) sx[r] = m * (1.0f / 127.0f);
    signed char q[16];
    #pragma unroll
    for (int j = 0; j < 4; ++j) {
      q[j * 4 + 0] = (signed char)__float2int_rn(v[j].x * inv);
      q[j * 4 + 1] = (signed char)__float2int_rn(v[j].y * inv);
      q[j * 4 + 2] = (signed char)__float2int_rn(v[j].z * inv);
      q[j * 4 + 3] = (signed char)__float2int_rn(v[j].w * inv);
    }
    ((int4*)xq)[(size_t)r * 256 + tid] = *(const int4*)q;
  } else {
    const int b = blockIdx.x - M;
    int4 v[4];
    #pragma unroll
    for (int j = 0; j < 4; ++j) v[j] = w[(size_t)b * 1024 + tid * 4 + j];
    signed char q[16];
    #pragma unroll
    for (int j = 0; j < 4; ++j) {
      q[j * 4 + 0] = (signed char)v[j].x; q[j * 4 + 1] = (signed char)v[j].y;
      q[j * 4 + 2] = (signed char)v[j].z; q[j * 4 + 3] = (signed char)v[j].w;
    }
    ((int4*)wq)[(size_t)b * 256 + tid] = *(const int4*)q;
  }
}

// ---------------------------------------------------------------------------
// C[M][N] = (Aq[M][K] . Bq[N][K]^T) * sx[M] * scaler[N]
//
// Round-2 structure: MINIMAL SYNC, MAX ASYNCHRONY.
//   tile 256x256, BK=64 (i8 rows = 64B), 512 thr = 8 waves (2M x 4N),
//   per-wave output 128x64, mfma_i32_16x16x64_i8.
// LDS: 4-deep ring, 4 x (sA 16KB + sB 16KB) = 128 KB. Stage 3 tiles ahead.
//   Tile t reads buf[t&3]; tile t stages t+3 into buf[(t+3)&3]==buf[(t-1)&3],
//   whose reads completed before the end-of-tile-(t-1) barrier -> exactly ONE
//   barrier per tile is necessary and sufficient. No phase barriers, no
//   setprio (2 waves/SIMD lockstep: setprio starves the sibling wave, m190).
// vmcnt: counted vmcnt(8) once per tile (allows stage(t+2)+stage(t+3) = 8
//   loads in flight; guarantees tile t+1 landed). Raw s_barrier (NOT
//   __syncthreads) so the compiler does not force a vmcnt(0) drain.
// Inner tile: 12 x ds_read_b128 + 32 MFMA, compiler-scheduled (it emits
//   fine-grained lgkmcnt interleave on its own — m97 asm evidence).
// Swizzle (64B rows, 4 x 16B slots): phys_slot = logical ^ ((row>>1)&3),
//   on the pre-swizzled GLOBAL source (LDS dest linear, as global_load_lds
//   requires) and on the ds_read address -> 0 bank conflicts (verified r1).
// ---------------------------------------------------------------------------
__global__ __launch_bounds__(512, 2) void gemm_i8_kernel(
    const signed char* __restrict__ A,   // [M][K] i8
    const signed char* __restrict__ B,   // [N][K] i8
    const float* __restrict__ sx,        // [M] x dequant scale
    const float* __restrict__ scaler,    // [N] weight scale
    float* __restrict__ C,               // [M][N] fp32
    int M, int N, int K)
{
  __shared__ signed char sA[4][256 * 64];   // 4 x 16 KB
  __shared__ signed char sB[4][256 * 64];   // 4 x 16 KB

  const int tid  = threadIdx.x;
  const int wave = tid >> 6;
  const int lane = tid & 63;
  const int bm = blockIdx.y << 8;
  const int bn = blockIdx.x << 8;

  const int wm = (wave >> 2) << 7;   // 0 or 128 : wave's M offset
  const int wn = (wave & 3) << 6;    // 0/64/128/192 : wave's N offset
  const int l15  = lane & 15;
  const int quad = lane >> 4;

  // Staging: thread t covers row (t>>2) (half 0) / 128+(t>>2) (half 1),
  // physical 16B slot (t&3); logical k-group = (t&3) ^ ((row>>1)&3).
  // ((row+128)>>1)&3 == (row>>1)&3, so one kg serves both halves.
  const int srow = tid >> 2;
  const int kg = (tid & 3) ^ ((srow >> 1) & 3);
  const signed char* ga = A + (size_t)(bm + srow) * K + kg * 16;
  const signed char* gb = B + (size_t)(bn + srow) * K + kg * 16;
  const size_t rstep = (size_t)128 * K;     // +128 rows (half 1)
  const int ldst = tid * 16;                // linear LDS dest

  // Fragment ds_read: row = (wm|wn) + frag*16 + l15, logical kgroup = quad,
  // phys = quad ^ ((l15>>1)&3)  (frag*16, wm, wn don't affect (row>>1)&3).
  const int pk   = (quad ^ ((l15 >> 1) & 3)) << 4;
  const int aoff = (wm + l15) * 64 + pk;    // + mi*1024 per fragment
  const int boff = (wn + l15) * 64 + pk;    // + ni*1024 per fragment

  i32x4 acc[8][4] = {};

  // STAGE(tt): 4 global_load_lds (A half0, A half1, B half0, B half1)
#define STAGE(tt) do { const int sb_ = (tt) & 3; const size_t ko_ = (size_t)(tt) * 64; \
    __builtin_amdgcn_global_load_lds((AS1 void*)(ga + ko_),         (AS3 void*)(&sA[sb_][ldst]),        16, 0, 0); \
    __builtin_amdgcn_global_load_lds((AS1 void*)(ga + ko_ + rstep), (AS3 void*)(&sA[sb_][8192 + ldst]), 16, 0, 0); \
    __builtin_amdgcn_global_load_lds((AS1 void*)(gb + ko_),         (AS3 void*)(&sB[sb_][ldst]),        16, 0, 0); \
    __builtin_amdgcn_global_load_lds((AS1 void*)(gb + ko_ + rstep), (AS3 void*)(&sB[sb_][8192 + ldst]), 16, 0, 0); } while (0)

  const int nt = K >> 6;                    // 64 K-tiles

  // Prologue: stage tiles 0,1,2 (12 loads); tile 0 ready when <=8 remain.
  STAGE(0); STAGE(1); STAGE(2);
  asm volatile("s_waitcnt vmcnt(8)" ::: "memory");
  __builtin_amdgcn_s_barrier();
  __builtin_amdgcn_sched_barrier(0);

  for (int t = 0; t < nt; ++t) {
    const signed char* la = sA[t & 3];
    const signed char* lb = sB[t & 3];

    if (t < nt - 3) STAGE(t + 3);           // into buf[(t-1)&3] — safe (1 barrier ago)

    i32x4 av[8], bv[4];
    #pragma unroll
    for (int ni = 0; ni < 4; ++ni) bv[ni] = *(const i32x4*)&lb[boff + ni * 1024];
    #pragma unroll
    for (int mi = 0; mi < 8; ++mi) av[mi] = *(const i32x4*)&la[aoff + mi * 1024];

    #pragma unroll
    for (int mi = 0; mi < 8; ++mi)
      #pragma unroll
      for (int ni = 0; ni < 4; ++ni)
        acc[mi][ni] = __builtin_amdgcn_mfma_i32_16x16x64_i8(av[mi], bv[ni], acc[mi][ni], 0, 0, 0);

    // Tile boundary: guarantee tile t+1 landed; keep newest 8 loads in flight.
    if (t < nt - 3)        asm volatile("s_waitcnt vmcnt(8)" ::: "memory");
    else if (t == nt - 3)  asm volatile("s_waitcnt vmcnt(4)" ::: "memory");
    else if (t == nt - 2)  asm volatile("s_waitcnt vmcnt(0)" ::: "memory");
    if (t < nt - 1) {
      __builtin_amdgcn_s_barrier();
      __builtin_amdgcn_sched_barrier(0);
    }
  }
#undef STAGE

  // Epilogue: C/D layout col=lane&15 (N), row=quad*4+reg (M) — dtype-indep.
  #pragma unroll
  for (int mi = 0; mi < 8; ++mi) {
    const int gm0 = bm + wm + mi * 16 + quad * 4;
    float sr[4];
    #pragma unroll
    for (int r = 0; r < 4; ++r) sr[r] = sx[gm0 + r];
    #pragma unroll
    for (int ni = 0; ni < 4; ++ni) {
      const int gn = bn + wn + ni * 16 + l15;
      const float sc = scaler[gn];
      #pragma unroll
      for (int r = 0; r < 4; ++r)
        C[(size_t)(gm0 + r) * N + gn] = (float)acc[mi][ni][r] * sr[r] * sc;
    }
  }
}

extern "C" void kernel_launch(void* const* d_in, const int* in_sizes, int n_in,
                              void* d_out, int out_size, void* d_ws, size_t ws_size,
                              hipStream_t stream) {
  const float* x  = (const float*)d_in[0];          // [B,S,K] fp32
  const int*   w  = (const int*)d_in[1];            // [N,K] int32 (int8 range)
  const float* sc = (const float*)d_in[2];          // [N] fp32
  float* out = (float*)d_out;

  const int N = in_sizes[2];                        // 4096
  const int K = in_sizes[1] / N;                    // 4096
  const int M = in_sizes[0] / K;                    // 4096

  signed char* Aq = (signed char*)d_ws;             // [M][K] i8
  signed char* Bq = Aq + (size_t)M * K;             // [N][K] i8
  float* sx = (float*)(Bq + (size_t)N * K);         // [M] fp32

  const int wBlocks = (N * K) / (256 * 16);         // 16 elems/thread
  quant_kernel<<<M + wBlocks, 256, 0, stream>>>(
      (const float4*)x, (const int4*)w, Aq, Bq, sx, M, K / 16);

  dim3 grid(N / 256, M / 256);
  gemm_i8_kernel<<<grid, 512, 0, stream>>>(Aq, Bq, sx, sc, out, M, N, K);
}

// Round 3
// 241.924 us; speedup vs baseline: 1.0419x; 1.0385x over previous
//
#include <hip/hip_runtime.h>

typedef int i32x4 __attribute__((ext_vector_type(4)));

#define AS1 __attribute__((address_space(1)))
#define AS3 __attribute__((address_space(3)))

// ---------------------------------------------------------------------------
// Quantize kernel (UNCHANGED, verified 3 rounds). Blocks [0, M): per-token
// dynamic quant of x row r (4096 fp32 -> int8, scale sx[r] = rowmax/127).
// Blocks [M, M+wB): narrow w int32 (values 0..126, exact) -> int8.
// ---------------------------------------------------------------------------
__global__ __launch_bounds__(256) void quant_kernel(
    const float4* __restrict__ x, const int4* __restrict__ w,
    signed char* __restrict__ xq, signed char* __restrict__ wq,
    float* __restrict__ sx, int M, int Kq) {
  const int tid = threadIdx.x;
  if ((int)blockIdx.x < M) {
    const int r = blockIdx.x;
    float4 v[4];
    #pragma unroll
    for (int j = 0; j < 4; ++j) v[j] = x[(size_t)r * 1024 + tid * 4 + j];
    float m = 0.f;
    #pragma unroll
    for (int j = 0; j < 4; ++j)
      m = fmaxf(m, fmaxf(fmaxf(fabsf(v[j].x), fabsf(v[j].y)),
                         fmaxf(fabsf(v[j].z), fabsf(v[j].w))));
    #pragma unroll
    for (int off = 1; off < 64; off <<= 1) m = fmaxf(m, __shfl_xor(m, off));
    __shared__ float wmax[4];
    if ((tid & 63) == 0) wmax[tid >> 6] = m;
    __syncthreads();
    m = fmaxf(fmaxf(wmax[0], wmax[1]), fmaxf(wmax[2], wmax[3]));
    const float inv = (m > 0.f) ? 127.0f / m : 0.f;
    if (tid == 0) sx[r] = m * (1.0f / 127.0f);
    signed char q[16];
    #pragma unroll
    for (int j = 0; j < 4; ++j) {
      q[j * 4 + 0] = (signed char)__float2int_rn(v[j].x * inv);
      q[j * 4 + 1] = (signed char)__float2int_rn(v[j].y * inv);
      q[j * 4 + 2] = (signed char)__float2int_rn(v[j].z * inv);
      q[j * 4 + 3] = (signed char)__float2int_rn(v[j].w * inv);
    }
    ((int4*)xq)[(size_t)r * 256 + tid] = *(const int4*)q;
  } else {
    const int b = blockIdx.x - M;
    int4 v[4];
    #pragma unroll
    for (int j = 0; j < 4; ++j) v[j] = w[(size_t)b * 1024 + tid * 4 + j];
    signed char q[16];
    #pragma unroll
    for (int j = 0; j < 4; ++j) {
      q[j * 4 + 0] = (signed char)v[j].x; q[j * 4 + 1] = (signed char)v[j].y;
      q[j * 4 + 2] = (signed char)v[j].z; q[j * 4 + 3] = (signed char)v[j].w;
    }
    ((int4*)wq)[(size_t)b * 256 + tid] = *(const int4*)q;
  }
}

// ---------------------------------------------------------------------------
// C[M][N] = (Aq[M][K] . Bq[N][K]^T) * sx[M] * scaler[N]
//
// Round-3: CROSS-BLOCK ASYNCHRONY. Same verified inner loop as r2 (identical
// addressing/swizzle/counted-vmcnt; absmax bit-identical 3 rounds), but:
//   tile 256(M) x 128(N), 256 thr = 4 waves (2M x 2N), per-wave 128x64 out,
//   LDS = 3-deep ring x (sA 16KB + sB 8KB) = 72 KB -> TWO blocks per CU.
// Each SIMD hosts 2 waves from DIFFERENT blocks with independent barriers:
// when one block stalls (barrier / vmcnt / ds-read latency / epilogue store
// burst) the other block's wave issues MFMAs. This was the one axis all
// three previous (equal-time) schedules lacked.
// setprio(1) around the MFMA cluster: with cross-block phase diversity the
// CU scheduler has something to arbitrate (m191 mechanism; m190's null was
// lockstep-only).
// Ring liveness: tile t reads buf[t%3]; stages t+2 into buf[(t+2)%3] ==
// buf[(t-1)%3], whose reads finished before the end-of-tile-(t-1) barrier
// -> one barrier/tile is necessary and sufficient.
// vmcnt: 6 loads/tile; steady-state wait vmcnt(6) keeps tile t+2's loads in
// flight while guaranteeing tile t+1 landed. Never drains in main loop.
// Swizzle (64B rows, 4 x 16B slots): phys_slot = logical ^ ((row>>1)&3), on
// the pre-swizzled GLOBAL source (LDS dest linear, as global_load_lds
// requires) and on the ds_read address -> 0 bank conflicts (verified).
// ---------------------------------------------------------------------------
__global__ __launch_bounds__(256, 2) void gemm_i8_kernel(
    const signed char* __restrict__ A,   // [M][K] i8
    const signed char* __restrict__ B,   // [N][K] i8
    const float* __restrict__ sx,        // [M] x dequant scale
    const float* __restrict__ scaler,    // [N] weight scale
    float* __restrict__ C,               // [M][N] fp32
    int M, int N, int K)
{
  __shared__ signed char sA[3][256 * 64];   // 3 x 16 KB
  __shared__ signed char sB[3][128 * 64];   // 3 x  8 KB

  const int tid  = threadIdx.x;
  const int wave = tid >> 6;
  const int lane = tid & 63;
  const int bm = blockIdx.y << 8;           // 256-row M tile
  const int bn = blockIdx.x << 7;           // 128-col N tile

  const int wm = (wave >> 1) << 7;   // 0 or 128 : wave's M offset
  const int wn = (wave & 1) << 6;    // 0 or 64  : wave's N offset
  const int l15  = lane & 15;
  const int quad = lane >> 4;

  // Staging: 256 threads, 16B each = 4KB per global_load_lds wave-set.
  // Thread t covers row j*64 + (t>>2) (j = set index), phys 16B slot (t&3);
  // logical k-group = (t&3) ^ ((row>>1)&3). j*64 preserves (row>>1)&3, so
  // one kg serves all sets.
  const int srow = tid >> 2;                      // 0..63
  const int kg = (tid & 3) ^ ((srow >> 1) & 3);
  const signed char* ga = A + (size_t)(bm + srow) * K + kg * 16;
  const signed char* gb = B + (size_t)(bn + srow) * K + kg * 16;
  const size_t rstep = (size_t)64 * K;            // +64 rows per set
  const int ldst = tid * 16;                      // linear LDS dest (4KB/set)

  // Fragment ds_read: row = (wm|wn) + frag*16 + l15, logical kgroup = quad,
  // phys = quad ^ ((l15>>1)&3)  (frag*16, wm, wn don't affect (row>>1)&3).
  const int pk   = (quad ^ ((l15 >> 1) & 3)) << 4;
  const int aoff = (wm + l15) * 64 + pk;    // + mi*1024 per fragment
  const int boff = (wn + l15) * 64 + pk;    // + ni*1024 per fragment

  i32x4 acc[8][4] = {};

  // STAGE(tt, sb): 6 global_load_lds — A rows [0,256) in 4 sets, B rows
  // [0,128) in 2 sets — into ring buffer sb.
#define STAGE(tt, sb) do { const size_t ko_ = (size_t)(tt) * 64;             \
    __builtin_amdgcn_global_load_lds((AS1 void*)(ga + ko_),             (AS3 void*)(&sA[sb][ldst]),         16, 0, 0); \
    __builtin_amdgcn_global_load_lds((AS1 void*)(ga + ko_ + rstep),     (AS3 void*)(&sA[sb][4096 + ldst]),  16, 0, 0); \
    __builtin_amdgcn_global_load_lds((AS1 void*)(ga + ko_ + 2 * rstep), (AS3 void*)(&sA[sb][8192 + ldst]),  16, 0, 0); \
    __builtin_amdgcn_global_load_lds((AS1 void*)(ga + ko_ + 3 * rstep), (AS3 void*)(&sA[sb][12288 + ldst]), 16, 0, 0); \
    __builtin_amdgcn_global_load_lds((AS1 void*)(gb + ko_),             (AS3 void*)(&sB[sb][ldst]),         16, 0, 0); \
    __builtin_amdgcn_global_load_lds((AS1 void*)(gb + ko_ + rstep),     (AS3 void*)(&sB[sb][4096 + ldst]),  16, 0, 0); } while (0)

  const int nt = K >> 6;                    // 64 K-tiles

  // Prologue: stage tiles 0,1 (12 loads); tile 0 ready when <=6 remain.
  STAGE(0, 0); STAGE(1, 1);
  asm volatile("s_waitcnt vmcnt(6)" ::: "memory");
  __builtin_amdgcn_s_barrier();
  __builtin_amdgcn_sched_barrier(0);

  int br = 0;                               // read buf  = t % 3
  int bs = 2;                               // stage buf = (t+2) % 3
  for (int t = 0; t < nt; ++t) {
    const signed char* la = sA[br];
    const signed char* lb = sB[br];

    if (t < nt - 2) STAGE(t + 2, bs);       // into buf[(t-1)%3] — safe (1 barrier ago)

    i32x4 av[8], bv[4];
    #pragma unroll
    for (int ni = 0; ni < 4; ++ni) bv[ni] = *(const i32x4*)&lb[boff + ni * 1024];
    #pragma unroll
    for (int mi = 0; mi < 8; ++mi) av[mi] = *(const i32x4*)&la[aoff + mi * 1024];

    __builtin_amdgcn_s_setprio(1);
    #pragma unroll
    for (int mi = 0; mi < 8; ++mi)
      #pragma unroll
      for (int ni = 0; ni < 4; ++ni)
        acc[mi][ni] = __builtin_amdgcn_mfma_i32_16x16x64_i8(av[mi], bv[ni], acc[mi][ni], 0, 0, 0);
    __builtin_amdgcn_s_setprio(0);

    // Tile boundary: guarantee tile t+1 landed; keep tile t+2's 6 in flight.
    if (t < nt - 2)        asm volatile("s_waitcnt vmcnt(6)" ::: "memory");
    else if (t == nt - 2)  asm volatile("s_waitcnt vmcnt(0)" ::: "memory");
    if (t < nt - 1) {
      __builtin_amdgcn_s_barrier();
      __builtin_amdgcn_sched_barrier(0);
    }
    br = (br == 2) ? 0 : br + 1;
    bs = (bs == 2) ? 0 : bs + 1;
  }
#undef STAGE

  // Epilogue: C/D layout col=lane&15 (N), row=quad*4+reg (M) — dtype-indep.
  #pragma unroll
  for (int mi = 0; mi < 8; ++mi) {
    const int gm0 = bm + wm + mi * 16 + quad * 4;
    float sr[4];
    #pragma unroll
    for (int r = 0; r < 4; ++r) sr[r] = sx[gm0 + r];
    #pragma unroll
    for (int ni = 0; ni < 4; ++ni) {
      const int gn = bn + wn + ni * 16 + l15;
      const float sc = scaler[gn];
      #pragma unroll
      for (int r = 0; r < 4; ++r)
        C[(size_t)(gm0 + r) * N + gn] = (float)acc[mi][ni][r] * sr[r] * sc;
    }
  }
}

extern "C" void kernel_launch(void* const* d_in, const int* in_sizes, int n_in,
                              void* d_out, int out_size, void* d_ws, size_t ws_size,
                              hipStream_t stream) {
  const float* x  = (const float*)d_in[0];          // [B,S,K] fp32
  const int*   w  = (const int*)d_in[1];            // [N,K] int32 (int8 range)
  const float* sc = (const float*)d_in[2];          // [N] fp32
  float* out = (float*)d_out;

  const int N = in_sizes[2];                        // 4096
  const int K = in_sizes[1] / N;                    // 4096
  const int M = in_sizes[0] / K;                    // 4096

  signed char* Aq = (signed char*)d_ws;             // [M][K] i8
  signed char* Bq = Aq + (size_t)M * K;             // [N][K] i8
  float* sx = (float*)(Bq + (size_t)N * K);         // [M] fp32

  const int wBlocks = (N * K) / (256 * 16);         // 16 elems/thread
  quant_kernel<<<M + wBlocks, 256, 0, stream>>>(
      (const float4*)x, (const int4*)w, Aq, Bq, sx, M, K / 16);

  dim3 grid(N / 128, M / 256);
  gemm_i8_kernel<<<grid, 256, 0, stream>>>(Aq, Bq, sx, sc, out, M, N, K);
}